// Round 1
// baseline (209.291 us; speedup 1.0000x reference)
//
#include <hip/hip_runtime.h>
#include <hip/hip_bf16.h>

// out[n,a,b,f,w] = 0.75*(x[n,a,f,u]*y[n,b,f,v] + x[n,b,f,u]*y[n,a,f,v])
//                  - 0.5*z[n,f,w]*(a==b),   w = u*2+v
// N=8192, F=128, P1=P2=2. One thread per (n,f). Pure streaming, memory-bound.

#define NN 8192
#define FF 128

__global__ __launch_bounds__(256) void tp_block2_kernel(
    const float* __restrict__ x,   // [N,3,F,2]
    const float* __restrict__ y,   // [N,3,F,2]
    const float* __restrict__ z,   // [N,F,4]
    float* __restrict__ out)       // [N,3,3,F,4]
{
    int t = blockIdx.x * blockDim.x + threadIdx.x;   // [0, N*F)
    int n = t >> 7;     // t / F
    int f = t & 127;    // t % F

    // x,y viewed as float2 over the trailing P dim: index (n*3 + a)*F + f
    const float2* x2p = reinterpret_cast<const float2*>(x);
    const float2* y2p = reinterpret_cast<const float2*>(y);

    float2 xa[3], ya[3];
#pragma unroll
    for (int a = 0; a < 3; ++a) {
        xa[a] = x2p[(n * 3 + a) * FF + f];
        ya[a] = y2p[(n * 3 + a) * FF + f];
    }
    float4 zz = reinterpret_cast<const float4*>(z)[n * FF + f];

    const float c  = 0.75f;   // NORM_112
    const float c2 = 0.5f;    // 0.75 * 2/3

    float4* outp = reinterpret_cast<float4*>(out);  // [N,3,3,F] of float4
#pragma unroll
    for (int a = 0; a < 3; ++a) {
#pragma unroll
        for (int b = 0; b < 3; ++b) {
            float4 r;
            // w = u*2 + v ; .x=(0,0) .y=(0,1) .z=(1,0) .w=(1,1)
            r.x = c * (xa[a].x * ya[b].x + xa[b].x * ya[a].x);
            r.y = c * (xa[a].x * ya[b].y + xa[b].x * ya[a].y);
            r.z = c * (xa[a].y * ya[b].x + xa[b].y * ya[a].x);
            r.w = c * (xa[a].y * ya[b].y + xa[b].y * ya[a].y);
            if (a == b) {
                r.x -= c2 * zz.x;
                r.y -= c2 * zz.y;
                r.z -= c2 * zz.z;
                r.w -= c2 * zz.w;
            }
            outp[((n * 9 + a * 3 + b) * FF + f)] = r;
        }
    }
}

extern "C" void kernel_launch(void* const* d_in, const int* in_sizes, int n_in,
                              void* d_out, int out_size, void* d_ws, size_t ws_size,
                              hipStream_t stream) {
    const float* x = (const float*)d_in[0];
    const float* y = (const float*)d_in[1];
    const float* z = (const float*)d_in[2];
    // d_in[3] is eye(3) — identity by construction, folded into the kernel.
    float* out = (float*)d_out;

    const int total = NN * FF;                 // 1,048,576 threads
    const int block = 256;
    const int grid = total / block;            // 4096 blocks
    tp_block2_kernel<<<grid, block, 0, stream>>>(x, y, z, out);
}